// Round 1
// baseline (810.749 us; speedup 1.0000x reference)
//
#include <hip/hip_runtime.h>
#include <hip/hip_bf16.h>

#define N_NODES 30000
#define N_EDGES 480000
#define DIM 512
#define NREL 4
#define NSEG (NREL * N_NODES)   // 120000
#define KTOT ((NREL + 1) * DIM) // 2560

typedef __attribute__((ext_vector_type(8))) short short8;
typedef __attribute__((ext_vector_type(4))) float f32x4;

__device__ __forceinline__ float bf2f(unsigned int hi) {
    union { unsigned int u; float f; } v; v.u = hi << 16; return v.f;
}
__device__ __forceinline__ unsigned short f2bf(float f) {
    union { float f; unsigned int u; } v; v.f = f;
    unsigned int u = v.u;
    unsigned int r = (u + 0x7fffu + ((u >> 16) & 1u)) >> 16;
    return (unsigned short)r;
}

// ---------------- prep: WcatT build (B^T layout: [e][k], k<512 -> root, else W[r]) -----
__global__ void k_wcat(const float* __restrict__ W, const float* __restrict__ root,
                       unsigned short* __restrict__ wt) {
    int i = blockIdx.x * 256 + threadIdx.x;       // over 512*2560, k fastest
    if (i >= DIM * KTOT) return;
    int k = i % KTOT, e = i / KTOT;
    float v;
    if (k < DIM) {
        v = root[k * DIM + e];
    } else {
        int kk = k - DIM;
        int r = kk >> 9; kk &= 511;
        v = W[(size_t)r * DIM * DIM + (size_t)kk * DIM + e];
    }
    wt[(size_t)e * KTOT + k] = f2bf(v);
}

// ---------------- prep: x0 = emb[x_idx] (f32 + bf16) ----------------
__global__ void k_embed(const int* __restrict__ xidx, const float* __restrict__ emb,
                        float* __restrict__ xf, unsigned short* __restrict__ xb) {
    int n = blockIdx.x;           // 30000
    int l = threadIdx.x;          // 64
    int id = xidx[n];
    const float4* er = (const float4*)(emb + (size_t)id * DIM + l * 8);
    float4 a = er[0], b = er[1];
    float4* xo = (float4*)(xf + (size_t)n * DIM + l * 8);
    xo[0] = a; xo[1] = b;
    ushort4 pa, pb;
    pa.x = f2bf(a.x); pa.y = f2bf(a.y); pa.z = f2bf(a.z); pa.w = f2bf(a.w);
    pb.x = f2bf(b.x); pb.y = f2bf(b.y); pb.z = f2bf(b.z); pb.w = f2bf(b.w);
    ushort4* xbo = (ushort4*)(xb + (size_t)n * DIM + l * 8);
    xbo[0] = pa; xbo[1] = pb;
}

// ---------------- counting sort of edges by seg = etype*N + dst ----------------
__global__ void k_hist(const int* __restrict__ etype, const int* __restrict__ dst,
                       int* __restrict__ hist) {
    int e = blockIdx.x * 256 + threadIdx.x;
    if (e < N_EDGES) atomicAdd(&hist[etype[e] * N_NODES + dst[e]], 1);
}

__global__ void k_scan1(const int* __restrict__ hist, int* __restrict__ offsets,
                        int* __restrict__ bsums) {
    __shared__ int sdata[256];
    int t = threadIdx.x, b = blockIdx.x;
    int base = b * 2048 + t * 8;
    int v[8]; int s = 0;
    #pragma unroll
    for (int i = 0; i < 8; i++) {
        int idx = base + i;
        v[i] = (idx < NSEG) ? hist[idx] : 0;
        s += v[i];
    }
    sdata[t] = s; __syncthreads();
    for (int off = 1; off < 256; off <<= 1) {
        int x = (t >= off) ? sdata[t - off] : 0;
        __syncthreads();
        sdata[t] += x;
        __syncthreads();
    }
    int run = (t == 0) ? 0 : sdata[t - 1];
    #pragma unroll
    for (int i = 0; i < 8; i++) {
        run += v[i];
        int idx = base + i;
        if (idx < NSEG) offsets[idx + 1] = run;  // inclusive-in-block, block offset added later
    }
    if (t == 255) bsums[b] = sdata[255];
}

__global__ void k_scan2(int* __restrict__ bsums, int nb) {
    if (threadIdx.x == 0 && blockIdx.x == 0) {
        int run = 0;
        for (int i = 0; i < nb; i++) { int v = bsums[i]; bsums[i] = run; run += v; }
    }
}

__global__ void k_scan3(const int* __restrict__ bsums, int* __restrict__ offsets) {
    int t = threadIdx.x, b = blockIdx.x;
    int base = b * 2048 + t * 8;
    int add = bsums[b];
    #pragma unroll
    for (int i = 0; i < 8; i++) {
        int idx = base + i;
        if (idx < NSEG) offsets[idx + 1] += add;
    }
    if (b == 0 && t == 0) offsets[0] = 0;
}

__global__ void k_scatter(const int* __restrict__ etype, const int* __restrict__ src,
                          const int* __restrict__ dst, const int* __restrict__ offsets,
                          int* __restrict__ cursor, int* __restrict__ ssrc) {
    int e = blockIdx.x * 256 + threadIdx.x;
    if (e < N_EDGES) {
        int seg = etype[e] * N_NODES + dst[e];
        int p = atomicAdd(&cursor[seg], 1);
        ssrc[offsets[seg] + p] = src[e];
    }
}

// ---------------- per-layer segment-mean (reads bf16 x, writes bf16 mean) ----------------
__global__ __launch_bounds__(256) void k_agg(const unsigned short* __restrict__ xb,
                                             const int* __restrict__ ssrc,
                                             const int* __restrict__ offsets,
                                             unsigned short* __restrict__ meanb) {
    int wid = threadIdx.x >> 6, lane = threadIdx.x & 63;
    int seg = blockIdx.x * 4 + wid;           // 30000 blocks * 4 waves = 120000 segs
    int st = offsets[seg], en = offsets[seg + 1];
    float acc[8] = {0, 0, 0, 0, 0, 0, 0, 0};
    for (int i = st; i < en; i++) {
        int s = ssrc[i];
        uint4 v = *(const uint4*)(xb + (size_t)s * DIM + lane * 8);
        acc[0] += bf2f(v.x & 0xffffu); acc[1] += bf2f(v.x >> 16);
        acc[2] += bf2f(v.y & 0xffffu); acc[3] += bf2f(v.y >> 16);
        acc[4] += bf2f(v.z & 0xffffu); acc[5] += bf2f(v.z >> 16);
        acc[6] += bf2f(v.w & 0xffffu); acc[7] += bf2f(v.w >> 16);
    }
    float inv = (en > st) ? 1.0f / (float)(en - st) : 0.0f;
    uint4 o;
    o.x = (unsigned int)f2bf(acc[0] * inv) | ((unsigned int)f2bf(acc[1] * inv) << 16);
    o.y = (unsigned int)f2bf(acc[2] * inv) | ((unsigned int)f2bf(acc[3] * inv) << 16);
    o.z = (unsigned int)f2bf(acc[4] * inv) | ((unsigned int)f2bf(acc[5] * inv) << 16);
    o.w = (unsigned int)f2bf(acc[6] * inv) | ((unsigned int)f2bf(acc[7] * inv) << 16);
    *(uint4*)(meanb + (size_t)seg * DIM + lane * 8) = o;
}

// ---------------- fused GEMM: C = [x|mean]@WcatT^T + bias, relu, +residual ----------------
#define GLD16(g, l)                                                                     \
    __builtin_amdgcn_global_load_lds((const __attribute__((address_space(1))) void*)(g), \
                                     (__attribute__((address_space(3))) void*)(l), 16, 0, 0)

__global__ __launch_bounds__(256) void k_gemm(const unsigned short* __restrict__ xb,
                                              const unsigned short* __restrict__ meanb,
                                              const unsigned short* __restrict__ wt,
                                              const float* __restrict__ bias,
                                              const float* xf, float* outf,
                                              unsigned short* __restrict__ xbn) {
    __shared__ unsigned short As[128 * 64];  // 16 KB
    __shared__ unsigned short Bs[128 * 64];  // 16 KB  (rows = output col e, cols = k)
    int tid = threadIdx.x;
    int lane = tid & 63, wid = tid >> 6;
    int bid = blockIdx.x;
    int bn = bid & 3, bm = bid >> 2;
    int m0 = bm * 128, n0 = bn * 128;
    int wm = wid >> 1, wn = wid & 1;

    f32x4 acc[4][4] = {};

    for (int kt = 0; kt < KTOT / 64; ++kt) {
        int p = kt >> 3;  // which A part: 0=x, 1..4=mean_r
        const unsigned short* abase = (p == 0) ? xb : meanb + (size_t)(p - 1) * N_NODES * DIM;
        int kcol0 = (kt & 7) * 64;
        // stage A tile: 128 rows x 64 k (bf16), 4 rounds of 256 lanes x 16B
        #pragma unroll
        for (int r = 0; r < 4; r++) {
            int c = r * 256 + tid;
            int row = c >> 3, kc = c & 7;
            int grow = m0 + row;
            if (grow >= N_NODES) grow = 0;  // clamp; masked at C write
            const unsigned short* g = abase + (size_t)grow * DIM + kcol0 + kc * 8;
            unsigned short* lbase = As + (size_t)(r * 256 + (wid << 6)) * 8;  // wave-uniform
            GLD16(g, lbase);
        }
        // stage B tile: 128 e-rows x 64 k
        #pragma unroll
        for (int r = 0; r < 4; r++) {
            int c = r * 256 + tid;
            int erow = c >> 3, kc = c & 7;
            const unsigned short* g = wt + (size_t)(n0 + erow) * KTOT + kt * 64 + kc * 8;
            unsigned short* lbase = Bs + (size_t)(r * 256 + (wid << 6)) * 8;
            GLD16(g, lbase);
        }
        __syncthreads();
        #pragma unroll
        for (int ks = 0; ks < 2; ks++) {
            short8 a[4], b[4];
            #pragma unroll
            for (int m = 0; m < 4; m++)
                a[m] = *(const short8*)(As + (size_t)(wm * 64 + m * 16 + (lane & 15)) * 64 +
                                        ks * 32 + (lane >> 4) * 8);
            #pragma unroll
            for (int n = 0; n < 4; n++)
                b[n] = *(const short8*)(Bs + (size_t)(wn * 64 + n * 16 + (lane & 15)) * 64 +
                                        ks * 32 + (lane >> 4) * 8);
            #pragma unroll
            for (int m = 0; m < 4; m++)
                #pragma unroll
                for (int n = 0; n < 4; n++)
                    acc[m][n] = __builtin_amdgcn_mfma_f32_16x16x32_bf16(a[m], b[n], acc[m][n], 0, 0, 0);
        }
        __syncthreads();
    }

    // epilogue: bias + relu + residual; write f32 out and bf16 next-x
    int rq = lane >> 4, cq = lane & 15;
    #pragma unroll
    for (int m = 0; m < 4; m++) {
        #pragma unroll
        for (int j = 0; j < 4; j++) {
            int row = m0 + wm * 64 + m * 16 + rq * 4 + j;
            if (row >= N_NODES) continue;
            #pragma unroll
            for (int n = 0; n < 4; n++) {
                int col = n0 + wn * 64 + n * 16 + cq;
                float v = acc[m][n][j] + bias[col];
                v = fmaxf(v, 0.0f) + xf[(size_t)row * DIM + col];
                outf[(size_t)row * DIM + col] = v;
                xbn[(size_t)row * DIM + col] = f2bf(v);
            }
        }
    }
}

extern "C" void kernel_launch(void* const* d_in, const int* in_sizes, int n_in,
                              void* d_out, int out_size, void* d_ws, size_t ws_size,
                              hipStream_t stream) {
    const int* xidx   = (const int*)d_in[0];
    const int* eidx   = (const int*)d_in[1];  // [0..E): src, [E..2E): dst
    const int* etype  = (const int*)d_in[2];
    const float* emb  = (const float*)d_in[3];
    const float* Wl[3]    = {(const float*)d_in[4], (const float*)d_in[7], (const float*)d_in[10]};
    const float* rootl[3] = {(const float*)d_in[5], (const float*)d_in[8], (const float*)d_in[11]};
    const float* bl[3]    = {(const float*)d_in[6], (const float*)d_in[9], (const float*)d_in[12]};
    const int* esrc = eidx;
    const int* edst = eidx + N_EDGES;

    char* ws = (char*)d_ws;
    size_t off = 0;
    auto take = [&](size_t bytes) { char* p = ws + off; off = (off + bytes + 255) & ~(size_t)255; return p; };
    float* xf            = (float*)take((size_t)N_NODES * DIM * 4);
    unsigned short* xb0  = (unsigned short*)take((size_t)N_NODES * DIM * 2);
    unsigned short* xb1  = (unsigned short*)take((size_t)N_NODES * DIM * 2);
    unsigned short* meanb= (unsigned short*)take((size_t)NREL * N_NODES * DIM * 2);
    unsigned short* wcat = (unsigned short*)take((size_t)3 * DIM * KTOT * 2);
    int* hist    = (int*)take((size_t)NSEG * 4);
    int* offsets = (int*)take((size_t)(NSEG + 1) * 4);
    int* cursor  = (int*)take((size_t)NSEG * 4);
    int* bsums   = (int*)take(64 * 4);
    int* ssrc    = (int*)take((size_t)N_EDGES * 4);

    // prep
    hipMemsetAsync(hist, 0, (size_t)NSEG * 4, stream);
    hipMemsetAsync(cursor, 0, (size_t)NSEG * 4, stream);
    for (int l = 0; l < 3; l++) {
        k_wcat<<<(DIM * KTOT + 255) / 256, 256, 0, stream>>>(Wl[l], rootl[l],
                                                             wcat + (size_t)l * DIM * KTOT);
    }
    k_embed<<<N_NODES, 64, 0, stream>>>(xidx, emb, xf, xb0);
    k_hist<<<(N_EDGES + 255) / 256, 256, 0, stream>>>(etype, edst, hist);
    k_scan1<<<(NSEG + 2047) / 2048, 256, 0, stream>>>(hist, offsets, bsums);
    k_scan2<<<1, 64, 0, stream>>>(bsums, (NSEG + 2047) / 2048);
    k_scan3<<<(NSEG + 2047) / 2048, 256, 0, stream>>>(bsums, offsets);
    k_scatter<<<(N_EDGES + 255) / 256, 256, 0, stream>>>(etype, esrc, edst, offsets, cursor, ssrc);

    // layers
    unsigned short* xb_cur = xb0;
    unsigned short* xb_nxt = xb1;
    const int ngemm = ((N_NODES + 127) / 128) * (DIM / 128);  // 235*4 = 940
    for (int l = 0; l < 3; l++) {
        k_agg<<<N_NODES, 256, 0, stream>>>(xb_cur, ssrc, offsets, meanb);
        float* of = (l == 2) ? (float*)d_out : xf;
        k_gemm<<<ngemm, 256, 0, stream>>>(xb_cur, meanb, wcat + (size_t)l * DIM * KTOT,
                                          bl[l], xf, of, xb_nxt);
        unsigned short* t = xb_cur; xb_cur = xb_nxt; xb_nxt = t;
    }
}

// Round 2
// 770.433 us; speedup vs baseline: 1.0523x; 1.0523x over previous
//
#include <hip/hip_runtime.h>
#include <hip/hip_bf16.h>

#define N_NODES 30000
#define N_EDGES 480000
#define DIM 512
#define NREL 4
#define NSEG (NREL * N_NODES)   // 120000
#define KTOT ((NREL + 1) * DIM) // 2560

typedef __attribute__((ext_vector_type(8))) short short8;
typedef __attribute__((ext_vector_type(4))) float f32x4;

__device__ __forceinline__ float bf2f(unsigned int hi) {
    union { unsigned int u; float f; } v; v.u = hi << 16; return v.f;
}
__device__ __forceinline__ unsigned short f2bf(float f) {
    union { float f; unsigned int u; } v; v.f = f;
    unsigned int u = v.u;
    unsigned int r = (u + 0x7fffu + ((u >> 16) & 1u)) >> 16;
    return (unsigned short)r;
}

// ---------------- prep: WcatT build (B^T layout: [e][k], k<512 -> root, else W[r]) -----
__global__ void k_wcat(const float* __restrict__ W, const float* __restrict__ root,
                       unsigned short* __restrict__ wt) {
    int i = blockIdx.x * 256 + threadIdx.x;       // over 512*2560, k fastest
    if (i >= DIM * KTOT) return;
    int k = i % KTOT, e = i / KTOT;
    float v;
    if (k < DIM) {
        v = root[k * DIM + e];
    } else {
        int kk = k - DIM;
        int r = kk >> 9; kk &= 511;
        v = W[(size_t)r * DIM * DIM + (size_t)kk * DIM + e];
    }
    wt[(size_t)e * KTOT + k] = f2bf(v);
}

// ---------------- prep: x0 = emb[x_idx] (bf16 only) ----------------
__global__ void k_embed(const int* __restrict__ xidx, const float* __restrict__ emb,
                        unsigned short* __restrict__ xb) {
    int n = blockIdx.x;           // 30000
    int l = threadIdx.x;          // 64
    int id = xidx[n];
    const float4* er = (const float4*)(emb + (size_t)id * DIM + l * 8);
    float4 a = er[0], b = er[1];
    ushort4 pa, pb;
    pa.x = f2bf(a.x); pa.y = f2bf(a.y); pa.z = f2bf(a.z); pa.w = f2bf(a.w);
    pb.x = f2bf(b.x); pb.y = f2bf(b.y); pb.z = f2bf(b.z); pb.w = f2bf(b.w);
    ushort4* xbo = (ushort4*)(xb + (size_t)n * DIM + l * 8);
    xbo[0] = pa; xbo[1] = pb;
}

// ---------------- counting sort of edges by seg = etype*N + dst ----------------
__global__ void k_hist(const int* __restrict__ etype, const int* __restrict__ dst,
                       int* __restrict__ hist) {
    int e = blockIdx.x * 256 + threadIdx.x;
    if (e < N_EDGES) atomicAdd(&hist[etype[e] * N_NODES + dst[e]], 1);
}

__global__ void k_scan1(const int* __restrict__ hist, int* __restrict__ offsets,
                        int* __restrict__ bsums) {
    __shared__ int sdata[256];
    int t = threadIdx.x, b = blockIdx.x;
    int base = b * 2048 + t * 8;
    int v[8]; int s = 0;
    #pragma unroll
    for (int i = 0; i < 8; i++) {
        int idx = base + i;
        v[i] = (idx < NSEG) ? hist[idx] : 0;
        s += v[i];
    }
    sdata[t] = s; __syncthreads();
    for (int off = 1; off < 256; off <<= 1) {
        int x = (t >= off) ? sdata[t - off] : 0;
        __syncthreads();
        sdata[t] += x;
        __syncthreads();
    }
    int run = (t == 0) ? 0 : sdata[t - 1];
    #pragma unroll
    for (int i = 0; i < 8; i++) {
        run += v[i];
        int idx = base + i;
        if (idx < NSEG) offsets[idx + 1] = run;  // block-local inclusive; block offset added later
    }
    if (t == 255) bsums[b] = sdata[255];
}

__global__ void k_scan2(int* __restrict__ bsums, int nb) {
    if (threadIdx.x == 0 && blockIdx.x == 0) {
        int run = 0;
        for (int i = 0; i < nb; i++) { int v = bsums[i]; bsums[i] = run; run += v; }
    }
}

__global__ void k_scan3(const int* __restrict__ bsums, int* __restrict__ offsets) {
    int t = threadIdx.x, b = blockIdx.x;
    int base = b * 2048 + t * 8;
    int add = bsums[b];
    #pragma unroll
    for (int i = 0; i < 8; i++) {
        int idx = base + i;
        if (idx < NSEG) offsets[idx + 1] += add;
    }
    if (b == 0 && t == 0) offsets[0] = 0;
}

__global__ void k_scatter(const int* __restrict__ etype, const int* __restrict__ src,
                          const int* __restrict__ dst, const int* __restrict__ offsets,
                          int* __restrict__ cursor, int* __restrict__ ssrc) {
    int e = blockIdx.x * 256 + threadIdx.x;
    if (e < N_EDGES) {
        int seg = etype[e] * N_NODES + dst[e];
        int p = atomicAdd(&cursor[seg], 1);
        ssrc[offsets[seg] + p] = src[e];
    }
}

// ---------------- per-layer segment-mean (reads bf16 x, writes bf16 mean) ----------------
__global__ __launch_bounds__(256) void k_agg(const unsigned short* __restrict__ xb,
                                             const int* __restrict__ ssrc,
                                             const int* __restrict__ offsets,
                                             unsigned short* __restrict__ meanb) {
    int wid = threadIdx.x >> 6, lane = threadIdx.x & 63;
    int seg = blockIdx.x * 4 + wid;           // 30000 blocks * 4 waves = 120000 segs
    int st = offsets[seg], en = offsets[seg + 1];
    float acc[8] = {0, 0, 0, 0, 0, 0, 0, 0};
    for (int i = st; i < en; i++) {
        int s = ssrc[i];
        uint4 v = *(const uint4*)(xb + (size_t)s * DIM + lane * 8);
        acc[0] += bf2f(v.x & 0xffffu); acc[1] += bf2f(v.x >> 16);
        acc[2] += bf2f(v.y & 0xffffu); acc[3] += bf2f(v.y >> 16);
        acc[4] += bf2f(v.z & 0xffffu); acc[5] += bf2f(v.z >> 16);
        acc[6] += bf2f(v.w & 0xffffu); acc[7] += bf2f(v.w >> 16);
    }
    float inv = (en > st) ? 1.0f / (float)(en - st) : 0.0f;
    uint4 o;
    o.x = (unsigned int)f2bf(acc[0] * inv) | ((unsigned int)f2bf(acc[1] * inv) << 16);
    o.y = (unsigned int)f2bf(acc[2] * inv) | ((unsigned int)f2bf(acc[3] * inv) << 16);
    o.z = (unsigned int)f2bf(acc[4] * inv) | ((unsigned int)f2bf(acc[5] * inv) << 16);
    o.w = (unsigned int)f2bf(acc[6] * inv) | ((unsigned int)f2bf(acc[7] * inv) << 16);
    *(uint4*)(meanb + (size_t)seg * DIM + lane * 8) = o;
}

// ---------------- fused GEMM: C = [x|mean]@WcatT^T + bias, relu, + bf16 residual --------
#define GLD16(g, l)                                                                     \
    __builtin_amdgcn_global_load_lds((const __attribute__((address_space(1))) void*)(g), \
                                     (__attribute__((address_space(3))) void*)(l), 16, 0, 0)

#define NWG_GEMM 940  // 235 row-panels * 4 col-panels

__global__ __launch_bounds__(256) void k_gemm(const unsigned short* __restrict__ xb,
                                              const unsigned short* __restrict__ meanb,
                                              const unsigned short* __restrict__ wt,
                                              const float* __restrict__ bias,
                                              float* __restrict__ outf,
                                              unsigned short* __restrict__ xbn,
                                              int wf32, int wbf16) {
    __shared__ unsigned short As[128 * 64];  // 16 KB
    __shared__ unsigned short Bs[128 * 64];  // 16 KB  (rows = output col e, cols = k)
    int tid = threadIdx.x;
    int lane = tid & 63, wid = tid >> 6;

    // bijective XCD swizzle (m204): chunk of ~118 consecutive logical ids per XCD,
    // bn fastest -> the 4 col-blocks sharing an A row-panel land on the same XCD's L2.
    int orig = blockIdx.x;
    int xcd = orig & 7, t = orig >> 3;
    const int q = NWG_GEMM >> 3, r = NWG_GEMM & 7;  // 117, 4
    int wgid = (xcd < r ? xcd * (q + 1) : r * (q + 1) + (xcd - r) * q) + t;
    int bn = wgid & 3, bm = wgid >> 2;
    int m0 = bm * 128, n0 = bn * 128;
    int wm = wid >> 1, wn = wid & 1;

    f32x4 acc[4][4] = {};

    for (int kt = 0; kt < KTOT / 64; ++kt) {
        int p = kt >> 3;  // which A part: 0=x, 1..4=mean_r
        const unsigned short* abase = (p == 0) ? xb : meanb + (size_t)(p - 1) * N_NODES * DIM;
        int kcol0 = (kt & 7) * 64;
        // stage A tile: 128 rows x 64 k (bf16), 4 rounds of 256 lanes x 16B
        #pragma unroll
        for (int rr = 0; rr < 4; rr++) {
            int c = rr * 256 + tid;
            int row = c >> 3, kc = c & 7;
            int grow = m0 + row;
            if (grow >= N_NODES) grow = 0;  // clamp; masked at C write
            const unsigned short* g = abase + (size_t)grow * DIM + kcol0 + kc * 8;
            unsigned short* lbase = As + (size_t)(rr * 256 + (wid << 6)) * 8;  // wave-uniform
            GLD16(g, lbase);
        }
        // stage B tile: 128 e-rows x 64 k
        #pragma unroll
        for (int rr = 0; rr < 4; rr++) {
            int c = rr * 256 + tid;
            int erow = c >> 3, kc = c & 7;
            const unsigned short* g = wt + (size_t)(n0 + erow) * KTOT + kt * 64 + kc * 8;
            unsigned short* lbase = Bs + (size_t)(rr * 256 + (wid << 6)) * 8;
            GLD16(g, lbase);
        }
        __syncthreads();
        #pragma unroll
        for (int ks = 0; ks < 2; ks++) {
            short8 a[4], b[4];
            #pragma unroll
            for (int m = 0; m < 4; m++)
                a[m] = *(const short8*)(As + (size_t)(wm * 64 + m * 16 + (lane & 15)) * 64 +
                                        ks * 32 + (lane >> 4) * 8);
            #pragma unroll
            for (int n = 0; n < 4; n++)
                b[n] = *(const short8*)(Bs + (size_t)(wn * 64 + n * 16 + (lane & 15)) * 64 +
                                        ks * 32 + (lane >> 4) * 8);
            #pragma unroll
            for (int m = 0; m < 4; m++)
                #pragma unroll
                for (int n = 0; n < 4; n++)
                    acc[m][n] = __builtin_amdgcn_mfma_f32_16x16x32_bf16(a[m], b[n], acc[m][n], 0, 0, 0);
        }
        __syncthreads();
    }

    // epilogue: bias + relu + bf16 residual (xb is also A part 0 -> L2-hot)
    int rq = lane >> 4, cq = lane & 15;
    #pragma unroll
    for (int m = 0; m < 4; m++) {
        #pragma unroll
        for (int j = 0; j < 4; j++) {
            int row = m0 + wm * 64 + m * 16 + rq * 4 + j;
            if (row >= N_NODES) continue;
            #pragma unroll
            for (int n = 0; n < 4; n++) {
                int col = n0 + wn * 64 + n * 16 + cq;
                float v = acc[m][n][j] + bias[col];
                v = fmaxf(v, 0.0f) + bf2f(xb[(size_t)row * DIM + col]);
                if (wf32)  outf[(size_t)row * DIM + col] = v;
                if (wbf16) xbn[(size_t)row * DIM + col] = f2bf(v);
            }
        }
    }
}

extern "C" void kernel_launch(void* const* d_in, const int* in_sizes, int n_in,
                              void* d_out, int out_size, void* d_ws, size_t ws_size,
                              hipStream_t stream) {
    const int* xidx   = (const int*)d_in[0];
    const int* eidx   = (const int*)d_in[1];  // [0..E): src, [E..2E): dst
    const int* etype  = (const int*)d_in[2];
    const float* emb  = (const float*)d_in[3];
    const float* Wl[3]    = {(const float*)d_in[4], (const float*)d_in[7], (const float*)d_in[10]};
    const float* rootl[3] = {(const float*)d_in[5], (const float*)d_in[8], (const float*)d_in[11]};
    const float* bl[3]    = {(const float*)d_in[6], (const float*)d_in[9], (const float*)d_in[12]};
    const int* esrc = eidx;
    const int* edst = eidx + N_EDGES;

    char* ws = (char*)d_ws;
    size_t off = 0;
    auto take = [&](size_t bytes) { char* p = ws + off; off = (off + bytes + 255) & ~(size_t)255; return p; };
    unsigned short* xb0  = (unsigned short*)take((size_t)N_NODES * DIM * 2);
    unsigned short* xb1  = (unsigned short*)take((size_t)N_NODES * DIM * 2);
    unsigned short* meanb= (unsigned short*)take((size_t)NREL * N_NODES * DIM * 2);
    unsigned short* wcat = (unsigned short*)take((size_t)3 * DIM * KTOT * 2);
    int* hist    = (int*)take((size_t)NSEG * 4);
    int* offsets = (int*)take((size_t)(NSEG + 1) * 4);
    int* cursor  = (int*)take((size_t)NSEG * 4);
    int* bsums   = (int*)take(64 * 4);
    int* ssrc    = (int*)take((size_t)N_EDGES * 4);

    // prep
    hipMemsetAsync(hist, 0, (size_t)NSEG * 4, stream);
    hipMemsetAsync(cursor, 0, (size_t)NSEG * 4, stream);
    for (int l = 0; l < 3; l++) {
        k_wcat<<<(DIM * KTOT + 255) / 256, 256, 0, stream>>>(Wl[l], rootl[l],
                                                             wcat + (size_t)l * DIM * KTOT);
    }
    k_embed<<<N_NODES, 64, 0, stream>>>(xidx, emb, xb0);
    k_hist<<<(N_EDGES + 255) / 256, 256, 0, stream>>>(etype, edst, hist);
    k_scan1<<<(NSEG + 2047) / 2048, 256, 0, stream>>>(hist, offsets, bsums);
    k_scan2<<<1, 64, 0, stream>>>(bsums, (NSEG + 2047) / 2048);
    k_scan3<<<(NSEG + 2047) / 2048, 256, 0, stream>>>(bsums, offsets);
    k_scatter<<<(N_EDGES + 255) / 256, 256, 0, stream>>>(etype, esrc, edst, offsets, cursor, ssrc);

    // layers
    unsigned short* xb_cur = xb0;
    unsigned short* xb_nxt = xb1;
    for (int l = 0; l < 3; l++) {
        k_agg<<<N_NODES, 256, 0, stream>>>(xb_cur, ssrc, offsets, meanb);
        int last = (l == 2);
        k_gemm<<<NWG_GEMM, 256, 0, stream>>>(xb_cur, meanb, wcat + (size_t)l * DIM * KTOT,
                                             bl[l], (float*)d_out, xb_nxt,
                                             last ? 1 : 0, last ? 0 : 1);
        unsigned short* t = xb_cur; xb_cur = xb_nxt; xb_nxt = t;
    }
}

// Round 5
// 656.270 us; speedup vs baseline: 1.2354x; 1.1740x over previous
//
#include <hip/hip_runtime.h>
#include <hip/hip_bf16.h>

#define N_NODES 30000
#define N_EDGES 480000
#define DIM 512
#define NREL 4
#define NSEG (NREL * N_NODES)   // 120000
#define KTOT ((NREL + 1) * DIM) // 2560
#define NT (KTOT / 64)          // 40 K-tiles of 64
#define NBM ((N_NODES + 255) / 256)  // 118
#define NWG_GEMM (NBM * 2)           // 236

typedef __attribute__((ext_vector_type(8))) short short8;
typedef __attribute__((ext_vector_type(4))) float f32x4;

__device__ __forceinline__ float bf2f(unsigned int hi) {
    union { unsigned int u; float f; } v; v.u = hi << 16; return v.f;
}
__device__ __forceinline__ unsigned short f2bf(float f) {
    union { float f; unsigned int u; } v; v.f = f;
    unsigned int u = v.u;
    unsigned int r = (u + 0x7fffu + ((u >> 16) & 1u)) >> 16;
    return (unsigned short)r;
}

// ---------------- prep: WcatT build (B^T layout: [e][k], k<512 -> root, else W[r]) -----
__global__ void k_wcat(const float* __restrict__ W, const float* __restrict__ root,
                       unsigned short* __restrict__ wt) {
    int i = blockIdx.x * 256 + threadIdx.x;       // over 512*2560, k fastest
    if (i >= DIM * KTOT) return;
    int k = i % KTOT, e = i / KTOT;
    float v;
    if (k < DIM) {
        v = root[k * DIM + e];
    } else {
        int kk = k - DIM;
        int r = kk >> 9; kk &= 511;
        v = W[(size_t)r * DIM * DIM + (size_t)kk * DIM + e];
    }
    wt[(size_t)e * KTOT + k] = f2bf(v);
}

// ---------------- prep: x0 = emb[x_idx] (bf16 only) ----------------
__global__ void k_embed(const int* __restrict__ xidx, const float* __restrict__ emb,
                        unsigned short* __restrict__ xb) {
    int n = blockIdx.x;           // 30000
    int l = threadIdx.x;          // 64
    int id = xidx[n];
    const float4* er = (const float4*)(emb + (size_t)id * DIM + l * 8);
    float4 a = er[0], b = er[1];
    ushort4 pa, pb;
    pa.x = f2bf(a.x); pa.y = f2bf(a.y); pa.z = f2bf(a.z); pa.w = f2bf(a.w);
    pb.x = f2bf(b.x); pb.y = f2bf(b.y); pb.z = f2bf(b.z); pb.w = f2bf(b.w);
    ushort4* xbo = (ushort4*)(xb + (size_t)n * DIM + l * 8);
    xbo[0] = pa; xbo[1] = pb;
}

// ---------------- counting sort of edges by seg = etype*N + dst ----------------
__global__ void k_hist(const int* __restrict__ etype, const int* __restrict__ dst,
                       int* __restrict__ hist) {
    int e = blockIdx.x * 256 + threadIdx.x;
    if (e < N_EDGES) atomicAdd(&hist[etype[e] * N_NODES + dst[e]], 1);
}

__global__ void k_scan1(const int* __restrict__ hist, int* __restrict__ offsets,
                        int* __restrict__ bsums) {
    __shared__ int sdata[256];
    int t = threadIdx.x, b = blockIdx.x;
    int base = b * 2048 + t * 8;
    int v[8]; int s = 0;
    #pragma unroll
    for (int i = 0; i < 8; i++) {
        int idx = base + i;
        v[i] = (idx < NSEG) ? hist[idx] : 0;
        s += v[i];
    }
    sdata[t] = s; __syncthreads();
    for (int off = 1; off < 256; off <<= 1) {
        int x = (t >= off) ? sdata[t - off] : 0;
        __syncthreads();
        sdata[t] += x;
        __syncthreads();
    }
    int run = (t == 0) ? 0 : sdata[t - 1];
    #pragma unroll
    for (int i = 0; i < 8; i++) {
        run += v[i];
        int idx = base + i;
        if (idx < NSEG) offsets[idx + 1] = run;
    }
    if (t == 255) bsums[b] = sdata[255];
}

__global__ void k_scan2(int* __restrict__ bsums, int nb) {
    if (threadIdx.x == 0 && blockIdx.x == 0) {
        int run = 0;
        for (int i = 0; i < nb; i++) { int v = bsums[i]; bsums[i] = run; run += v; }
    }
}

__global__ void k_scan3(const int* __restrict__ bsums, int* __restrict__ offsets) {
    int t = threadIdx.x, b = blockIdx.x;
    int base = b * 2048 + t * 8;
    int add = bsums[b];
    #pragma unroll
    for (int i = 0; i < 8; i++) {
        int idx = base + i;
        if (idx < NSEG) offsets[idx + 1] += add;
    }
    if (b == 0 && t == 0) offsets[0] = 0;
}

__global__ void k_scatter(const int* __restrict__ etype, const int* __restrict__ src,
                          const int* __restrict__ dst, const int* __restrict__ offsets,
                          int* __restrict__ cursor, int* __restrict__ ssrc) {
    int e = blockIdx.x * 256 + threadIdx.x;
    if (e < N_EDGES) {
        int seg = etype[e] * N_NODES + dst[e];
        int p = atomicAdd(&cursor[seg], 1);
        ssrc[offsets[seg] + p] = src[e];
    }
}

// ---------------- per-layer segment-mean (reads bf16 x, writes bf16 mean) ----------------
__global__ __launch_bounds__(256) void k_agg(const unsigned short* __restrict__ xb,
                                             const int* __restrict__ ssrc,
                                             const int* __restrict__ offsets,
                                             unsigned short* __restrict__ meanb) {
    int wid = threadIdx.x >> 6, lane = threadIdx.x & 63;
    int seg = blockIdx.x * 4 + wid;
    int st = offsets[seg], en = offsets[seg + 1];
    float acc[8] = {0, 0, 0, 0, 0, 0, 0, 0};
    for (int i = st; i < en; i++) {
        int s = ssrc[i];
        uint4 v = *(const uint4*)(xb + (size_t)s * DIM + lane * 8);
        acc[0] += bf2f(v.x & 0xffffu); acc[1] += bf2f(v.x >> 16);
        acc[2] += bf2f(v.y & 0xffffu); acc[3] += bf2f(v.y >> 16);
        acc[4] += bf2f(v.z & 0xffffu); acc[5] += bf2f(v.z >> 16);
        acc[6] += bf2f(v.w & 0xffffu); acc[7] += bf2f(v.w >> 16);
    }
    float inv = (en > st) ? 1.0f / (float)(en - st) : 0.0f;
    uint4 o;
    o.x = (unsigned int)f2bf(acc[0] * inv) | ((unsigned int)f2bf(acc[1] * inv) << 16);
    o.y = (unsigned int)f2bf(acc[2] * inv) | ((unsigned int)f2bf(acc[3] * inv) << 16);
    o.z = (unsigned int)f2bf(acc[4] * inv) | ((unsigned int)f2bf(acc[5] * inv) << 16);
    o.w = (unsigned int)f2bf(acc[6] * inv) | ((unsigned int)f2bf(acc[7] * inv) << 16);
    *(uint4*)(meanb + (size_t)seg * DIM + lane * 8) = o;
}

// ======================= 8-phase 256x256 GEMM (T2+T3+T4+T5) =======================
// A = [xb | meanb_r] (M=30000 x K=2560 bf16), B^T = wt (512 x 2560 bf16)
// Tiles: BM=BN=256, BK=64. 8 waves (2M x 4N), per-wave C = 128x64.
// LDS 128KB: buf{0,1} x {A k0, A k1, B k0, B k1} x [256 rows][32 k] bf16 (16KB each).
// Even K-tiles -> buf0, odd -> buf1. Staging granularity = one 16KB half-slot per
// phase; each phase stages the slot that retired last phase. vmcnt(6) only at
// phases 4 & 8 (ledger hand-verified); tail iterations w/o stages use vmcnt(0).
// Swizzle (both-sides involution, rule #21): chunk-col ^= (row + row>>2)&3,
// applied to the global SOURCE column at stage time and to the ds_read column.
// NOTE (round-5 fix): A's staged column is PART-relative ((tile&7)*64, each part
// has its own base pointer); B's column into wt is the FULL k = tile*64.

#define GLD16(g, l)                                                                     \
    __builtin_amdgcn_global_load_lds((const __attribute__((address_space(1))) void*)(g), \
                                     (__attribute__((address_space(3))) void*)(l), 16, 0, 0)

#define STAGE_A(tile, ksh, bufo) do {                                                   \
    int _pt = (tile) >> 3;                                                              \
    const unsigned short* _ab = (_pt == 0) ? xb : meanb + (size_t)(_pt - 1) * N_NODES * DIM; \
    int _kc = (((tile) & 7) << 6) + ((ksh) << 5) + gcol;                                \
    int _g0 = m0 + srow; if (_g0 >= N_NODES) _g0 = 0;                                   \
    int _g1 = m0 + srow + 128; if (_g1 >= N_NODES) _g1 = 0;                             \
    GLD16(_ab + (size_t)_g0 * DIM + _kc, S + (bufo) + ((ksh) * 8192) + (wid << 9));     \
    GLD16(_ab + (size_t)_g1 * DIM + _kc, S + (bufo) + ((ksh) * 8192) + 4096 + (wid << 9)); \
} while (0)

#define STAGE_B(tile, ksh, bufo) do {                                                   \
    int _kc = ((tile) << 6) + ((ksh) << 5) + gcol;  /* FULL k into wt (round-5 fix) */  \
    const unsigned short* _w0 = wt + (size_t)(n0 + srow) * KTOT + _kc;                  \
    GLD16(_w0, S + (bufo) + 16384 + ((ksh) * 8192) + (wid << 9));                       \
    GLD16(_w0 + (size_t)128 * KTOT, S + (bufo) + 16384 + ((ksh) * 8192) + 4096 + (wid << 9)); \
} while (0)

// arowF/brow0 are PRE-multiplied row bases (shorts). mq offset = 64 rows = 2048 shorts.
#define READ_A(mq, ks, bufo) do {                                                       \
    const unsigned short* _ap = S + (bufo) + (ks) * 8192 + arowF + (mq) * 2048 + cofs;  \
    a[0] = *(const short8*)(_ap);                                                       \
    a[1] = *(const short8*)(_ap + 512);                                                 \
    a[2] = *(const short8*)(_ap + 1024);                                                \
    a[3] = *(const short8*)(_ap + 1536);                                                \
} while (0)

#define READ_B(ks, bufo) do {                                                           \
    const unsigned short* _bp = S + (bufo) + 16384 + (ks) * 8192 + brow0 + cofs;        \
    b[0] = *(const short8*)(_bp);                                                       \
    b[1] = *(const short8*)(_bp + 512);                                                 \
    b[2] = *(const short8*)(_bp + 1024);                                                \
    b[3] = *(const short8*)(_bp + 1536);                                                \
} while (0)

#define MFMA16(mq) do {                                                                 \
    _Pragma("unroll") for (int _m = 0; _m < 4; ++_m)                                    \
    _Pragma("unroll") for (int _n = 0; _n < 4; ++_n)                                    \
        acc[(mq) * 4 + _m][_n] =                                                        \
            __builtin_amdgcn_mfma_f32_16x16x32_bf16(a[_m], b[_n], acc[(mq) * 4 + _m][_n], 0, 0, 0); \
} while (0)

#define PH_TOP()  __builtin_amdgcn_s_barrier();                                         \
                  asm volatile("s_waitcnt lgkmcnt(0)" ::: "memory");                    \
                  __builtin_amdgcn_sched_barrier(0);                                    \
                  __builtin_amdgcn_s_setprio(1)
#define PH_BOT()  __builtin_amdgcn_s_setprio(0); __builtin_amdgcn_sched_barrier(0);     \
                  __builtin_amdgcn_s_barrier()
#define VMC6()    asm volatile("s_waitcnt vmcnt(6)" ::: "memory")
#define VMC0()    asm volatile("s_waitcnt vmcnt(0)" ::: "memory")

__global__ __launch_bounds__(512, 2) void k_gemm(const unsigned short* __restrict__ xb,
                                                 const unsigned short* __restrict__ meanb,
                                                 const unsigned short* __restrict__ wt,
                                                 const float* __restrict__ bias,
                                                 float* __restrict__ outf,
                                                 unsigned short* __restrict__ xbn,
                                                 int wf32, int wbf16) {
    extern __shared__ unsigned short S[];  // 131072 B
    int tid = threadIdx.x;
    int lane = tid & 63, wid = tid >> 6;

    // bijective XCD swizzle (m204): bn fastest so the 2 col-blocks of a row-panel
    // land on the same XCD's L2.
    int orig = blockIdx.x;
    int xcd = orig & 7, tix = orig >> 3;
    const int q = NWG_GEMM >> 3, r = NWG_GEMM & 7;  // 29, 4
    int wgid = (xcd < r ? xcd * (q + 1) : r * (q + 1) + (xcd - r) * q) + tix;
    int bn = wgid & 1, bm = wgid >> 1;
    int m0 = bm * 256, n0 = bn * 256;
    int wm = wid >> 2, wn = wid & 3;

    // ds_read-side constants; swizzle f depends only on r15 (invariant under +16k rows)
    int r15 = lane & 15, c4 = lane >> 4;
    int f = (r15 + (r15 >> 2)) & 3;
    int cofs = ((c4 ^ f) << 3);              // shorts
    int arowF = (wm * 128 + r15) * 32;       // row base, shorts
    int brow0 = (wn * 64 + r15) * 32;

    // stage-side constants (f_t invariant under +128 rows)
    int srow = tid >> 2;                     // 0..127
    int f_t = (srow + (srow >> 2)) & 3;
    int gcol = (((tid & 3) ^ f_t) << 3);     // pre-swizzled global source col (elements)

    short8 a[4], b[4];
    f32x4 acc[8][4] = {};

    // prologue: tile0 -> buf0 (4 slots), tile1 -> buf1 (3 slots); 14 loads
    STAGE_B(0, 0, 0); STAGE_A(0, 0, 0); STAGE_B(0, 1, 0); STAGE_A(0, 1, 0);
    STAGE_B(1, 0, 32768); STAGE_A(1, 0, 32768); STAGE_B(1, 1, 32768);
    VMC6();                                   // tile0's 8 loads landed
    __builtin_amdgcn_s_barrier();

    for (int it = 0; it < NT / 2; ++it) {
        int t1 = 2 * it + 1, t2 = 2 * it + 2, t3 = 2 * it + 3;
        // ph1: tile t ks0 mq0          | stage t+1 A-k1 -> buf1
        READ_A(0, 0, 0); READ_B(0, 0);
        STAGE_A(t1, 1, 32768);
        PH_TOP(); MFMA16(0); PH_BOT();
        // ph2: ks0 mq1                 | stage t+2 B-k0 -> buf0
        READ_A(1, 0, 0);
        if (t2 < NT) STAGE_B(t2, 0, 0);
        PH_TOP(); MFMA16(1); PH_BOT();
        // ph3: ks1 mq0                 | stage t+2 A-k0 -> buf0
        READ_A(0, 1, 0); READ_B(1, 0);
        if (t2 < NT) STAGE_A(t2, 0, 0);
        PH_TOP(); MFMA16(0); PH_BOT();
        // ph4: ks1 mq1                 | stage t+2 B-k1 -> buf0 | vmcnt
        READ_A(1, 1, 0);
        if (t2 < NT) { STAGE_B(t2, 1, 0); VMC6(); } else { VMC0(); }
        PH_TOP(); MFMA16(1); PH_BOT();
        // ph5: tile t+1 ks0 mq0        | stage t+2 A-k1 -> buf0
        READ_A(0, 0, 32768); READ_B(0, 32768);
        if (t2 < NT) STAGE_A(t2, 1, 0);
        PH_TOP(); MFMA16(0); PH_BOT();
        // ph6: ks0 mq1                 | stage t+3 B-k0 -> buf1
        READ_A(1, 0, 32768);
        if (t3 < NT) STAGE_B(t3, 0, 32768);
        PH_TOP(); MFMA16(1); PH_BOT();
        // ph7: ks1 mq0                 | stage t+3 A-k0 -> buf1
        READ_A(0, 1, 32768); READ_B(1, 32768);
        if (t3 < NT) STAGE_A(t3, 0, 32768);
        PH_TOP(); MFMA16(0); PH_BOT();
        // ph8: ks1 mq1                 | stage t+3 B-k1 -> buf1 | vmcnt
        READ_A(1, 1, 32768);
        if (t3 < NT) { STAGE_B(t3, 1, 32768); VMC6(); } else { VMC0(); }
        PH_TOP(); MFMA16(1); PH_BOT();
    }
    VMC0();

    // epilogue: bias + relu + bf16 residual (xb is also A part 0 -> cache-hot)
    #pragma unroll
    for (int mm = 0; mm < 8; ++mm) {
        int rowoff = ((mm >> 2) << 6) + ((mm & 3) << 4);
        #pragma unroll
        for (int j = 0; j < 4; ++j) {
            int row = m0 + wm * 128 + rowoff + c4 * 4 + j;
            if (row >= N_NODES) continue;
            #pragma unroll
            for (int n = 0; n < 4; ++n) {
                int col = n0 + wn * 64 + n * 16 + r15;
                float v = acc[mm][n][j] + bias[col];
                v = fmaxf(v, 0.0f) + bf2f(xb[(size_t)row * DIM + col]);
                if (wf32)  outf[(size_t)row * DIM + col] = v;
                if (wbf16) xbn[(size_t)row * DIM + col] = f2bf(v);
            }
        }
    }
}

extern "C" void kernel_launch(void* const* d_in, const int* in_sizes, int n_in,
                              void* d_out, int out_size, void* d_ws, size_t ws_size,
                              hipStream_t stream) {
    const int* xidx   = (const int*)d_in[0];
    const int* eidx   = (const int*)d_in[1];
    const int* etype  = (const int*)d_in[2];
    const float* emb  = (const float*)d_in[3];
    const float* Wl[3]    = {(const float*)d_in[4], (const float*)d_in[7], (const float*)d_in[10]};
    const float* rootl[3] = {(const float*)d_in[5], (const float*)d_in[8], (const float*)d_in[11]};
    const float* bl[3]    = {(const float*)d_in[6], (const float*)d_in[9], (const float*)d_in[12]};
    const int* esrc = eidx;
    const int* edst = eidx + N_EDGES;

    char* ws = (char*)d_ws;
    size_t off = 0;
    auto take = [&](size_t bytes) { char* p = ws + off; off = (off + bytes + 255) & ~(size_t)255; return p; };
    unsigned short* xb0  = (unsigned short*)take((size_t)N_NODES * DIM * 2);
    unsigned short* xb1  = (unsigned short*)take((size_t)N_NODES * DIM * 2);
    unsigned short* meanb= (unsigned short*)take((size_t)NREL * N_NODES * DIM * 2);
    unsigned short* wcat = (unsigned short*)take((size_t)3 * DIM * KTOT * 2);
    int* hist    = (int*)take((size_t)NSEG * 4);
    int* offsets = (int*)take((size_t)(NSEG + 1) * 4);
    int* cursor  = (int*)take((size_t)NSEG * 4);
    int* bsums   = (int*)take(64 * 4);
    int* ssrc    = (int*)take((size_t)N_EDGES * 4);

    hipMemsetAsync(hist, 0, (size_t)NSEG * 4, stream);
    hipMemsetAsync(cursor, 0, (size_t)NSEG * 4, stream);
    for (int l = 0; l < 3; l++) {
        k_wcat<<<(DIM * KTOT + 255) / 256, 256, 0, stream>>>(Wl[l], rootl[l],
                                                             wcat + (size_t)l * DIM * KTOT);
    }
    k_embed<<<N_NODES, 64, 0, stream>>>(xidx, emb, xb0);
    k_hist<<<(N_EDGES + 255) / 256, 256, 0, stream>>>(etype, edst, hist);
    k_scan1<<<(NSEG + 2047) / 2048, 256, 0, stream>>>(hist, offsets, bsums);
    k_scan2<<<1, 64, 0, stream>>>(bsums, (NSEG + 2047) / 2048);
    k_scan3<<<(NSEG + 2047) / 2048, 256, 0, stream>>>(bsums, offsets);
    k_scatter<<<(N_EDGES + 255) / 256, 256, 0, stream>>>(etype, esrc, edst, offsets, cursor, ssrc);

    unsigned short* xb_cur = xb0;
    unsigned short* xb_nxt = xb1;
    for (int l = 0; l < 3; l++) {
        k_agg<<<N_NODES, 256, 0, stream>>>(xb_cur, ssrc, offsets, meanb);
        int last = (l == 2);
        k_gemm<<<NWG_GEMM, 512, 131072, stream>>>(xb_cur, meanb, wcat + (size_t)l * DIM * KTOT,
                                                  bl[l], (float*)d_out, xb_nxt,
                                                  last ? 1 : 0, last ? 0 : 1);
        unsigned short* t = xb_cur; xb_cur = xb_nxt; xb_nxt = t;
    }
}